// Round 7
// baseline (1100.551 us; speedup 1.0000x reference)
//
#include <hip/hip_runtime.h>
#include <math.h>

#define BATCH 4
#define C 512
#define N 4096   // content spatial (64*64)
#define M 4096   // style spatial (64*64)
#define MSPLIT 4

typedef __attribute__((ext_vector_type(8))) short short8;
typedef __attribute__((ext_vector_type(8))) __bf16 bf16x8;
typedef __attribute__((ext_vector_type(4))) float f32x4;

static __device__ __forceinline__ unsigned short f2bf(float x) {
    unsigned u = __float_as_uint(x);
    u += 0x7fff + ((u >> 16) & 1);          // round-to-nearest-even
    return (unsigned short)(u >> 16);
}
static __device__ __forceinline__ float bf2f(unsigned short h) {
    return __uint_as_float(((unsigned)h) << 16);
}
static __device__ __forceinline__ f32x4 mfma_bf16(short8 a, short8 b, f32x4 c) {
    return __builtin_amdgcn_mfma_f32_16x16x32_bf16(
        __builtin_bit_cast(bf16x8, a), __builtin_bit_cast(bf16x8, b), c, 0, 0, 0);
}
// direct global->LDS DMA, 16B per lane; lds dest must be wave-uniform base
static __device__ __forceinline__ void gload16(const void* g, void* l) {
    __builtin_amdgcn_global_load_lds(
        (const __attribute__((address_space(1))) void*)g,
        (__attribute__((address_space(3))) void*)l, 16, 0, 0);
}

// ---------------------------------------------------------------------------
// K0: split W (512x512 fp32) into bf16 hi/lo, once per call
// ---------------------------------------------------------------------------
__global__ __launch_bounds__(256) void wsplit_kernel(
    const float* __restrict__ W, unsigned short* __restrict__ hi,
    unsigned short* __restrict__ lo)
{
    int i = blockIdx.x * 256 + threadIdx.x;
    float v = W[i];
    unsigned short h = f2bf(v);
    hi[i] = h;
    lo[i] = f2bf(v - bf2f(h));
}

// ---------------------------------------------------------------------------
// K1a: MFMA linear for Fq/Gt: out[n][o] (hi/lo bf16), o fastest.
// block 64n x 64o, BK=32, waves 2x2 (wave tile 32n x 32o)
// ---------------------------------------------------------------------------
__global__ __launch_bounds__(256) void linear_fg_mfma(
    const float* __restrict__ in,                     // [C][N] batch slice
    const unsigned short* __restrict__ Whi, const unsigned short* __restrict__ Wlo,
    const float* __restrict__ bias,
    unsigned short* __restrict__ out_hi, unsigned short* __restrict__ out_lo)
{
    __shared__ float in_s[32][68];                    // [k][n] fp32
    __shared__ __align__(16) unsigned short wh_s[64][40];  // [o][k]
    __shared__ __align__(16) unsigned short wl_s[64][40];
    const int tid = threadIdx.x;
    const int n0 = blockIdx.x * 64, o0 = blockIdx.y * 64;
    const int w = tid >> 6, lane = tid & 63;
    const int wrow = w >> 1, wcol = w & 1;
    const int lr = lane & 15, q = lane >> 4;
    f32x4 acc[2][2];
    #pragma unroll
    for (int i = 0; i < 2; ++i)
        #pragma unroll
        for (int j = 0; j < 2; ++j) acc[i][j] = (f32x4){0.f, 0.f, 0.f, 0.f};

    for (int kc = 0; kc < C; kc += 32) {
        __syncthreads();
        #pragma unroll
        for (int it = 0; it < 2; ++it) {
            int idx = tid + it * 256;
            int k = idx >> 4, seg = idx & 15;
            *(float4*)&in_s[k][seg * 4] =
                *(const float4*)&in[(size_t)(kc + k) * N + n0 + seg * 4];
        }
        {
            int o = tid >> 2, sg = tid & 3;
            *(float4*)&wh_s[o][sg * 8] = *(const float4*)&Whi[(size_t)(o0 + o) * 512 + kc + sg * 8];
            *(float4*)&wl_s[o][sg * 8] = *(const float4*)&Wlo[(size_t)(o0 + o) * 512 + kc + sg * 8];
        }
        __syncthreads();
        short8 ah[2], al[2], bh[2], bl[2];
        #pragma unroll
        for (int i = 0; i < 2; ++i) {
            int n = wrow * 32 + i * 16 + lr;
            #pragma unroll
            for (int j = 0; j < 8; ++j) {
                float f = in_s[q * 8 + j][n];
                unsigned short h = f2bf(f);
                ah[i][j] = (short)h;
                al[i][j] = (short)f2bf(f - bf2f(h));
            }
        }
        #pragma unroll
        for (int j = 0; j < 2; ++j) {
            int o = wcol * 32 + j * 16 + lr;
            bh[j] = *(const short8*)&wh_s[o][q * 8];
            bl[j] = *(const short8*)&wl_s[o][q * 8];
        }
        #pragma unroll
        for (int i = 0; i < 2; ++i)
            #pragma unroll
            for (int j = 0; j < 2; ++j) {
                acc[i][j] = mfma_bf16(ah[i], bh[j], acc[i][j]);
                acc[i][j] = mfma_bf16(ah[i], bl[j], acc[i][j]);
                acc[i][j] = mfma_bf16(al[i], bh[j], acc[i][j]);
            }
    }
    #pragma unroll
    for (int i = 0; i < 2; ++i)
        #pragma unroll
        for (int j = 0; j < 2; ++j) {
            int o = o0 + wcol * 32 + j * 16 + lr;
            float bo = bias[o];
            #pragma unroll
            for (int r = 0; r < 4; ++r) {
                int n = n0 + wrow * 32 + i * 16 + q * 4 + r;
                float v = acc[i][j][r] + bo;
                unsigned short h = f2bf(v);
                out_hi[(size_t)n * 512 + o] = h;
                out_lo[(size_t)n * 512 + o] = f2bf(v - bf2f(h));
            }
        }
}

// ---------------------------------------------------------------------------
// K1b: MFMA linear for V: vhT[o][m] + precomputed v2hT/v2lT = hi/lo of vh^2
// ---------------------------------------------------------------------------
__global__ __launch_bounds__(256) void linear_v_mfma(
    const float* __restrict__ in,                     // [C][M] batch slice
    const unsigned short* __restrict__ Whi, const unsigned short* __restrict__ Wlo,
    const float* __restrict__ bias,
    unsigned short* __restrict__ vhT, unsigned short* __restrict__ v2hT,
    unsigned short* __restrict__ v2lT)
{
    __shared__ float in_s[32][68];                    // [k][m]
    __shared__ __align__(16) unsigned short wh_s[64][40];
    __shared__ __align__(16) unsigned short wl_s[64][40];
    const int tid = threadIdx.x;
    const int m0 = blockIdx.x * 64, o0 = blockIdx.y * 64;
    const int w = tid >> 6, lane = tid & 63;
    const int wrow = w >> 1, wcol = w & 1;
    const int lr = lane & 15, q = lane >> 4;
    f32x4 acc[2][2];
    #pragma unroll
    for (int i = 0; i < 2; ++i)
        #pragma unroll
        for (int j = 0; j < 2; ++j) acc[i][j] = (f32x4){0.f, 0.f, 0.f, 0.f};

    for (int kc = 0; kc < C; kc += 32) {
        __syncthreads();
        #pragma unroll
        for (int it = 0; it < 2; ++it) {
            int idx = tid + it * 256;
            int k = idx >> 4, seg = idx & 15;
            *(float4*)&in_s[k][seg * 4] =
                *(const float4*)&in[(size_t)(kc + k) * N + m0 + seg * 4];
        }
        {
            int o = tid >> 2, sg = tid & 3;
            *(float4*)&wh_s[o][sg * 8] = *(const float4*)&Whi[(size_t)(o0 + o) * 512 + kc + sg * 8];
            *(float4*)&wl_s[o][sg * 8] = *(const float4*)&Wlo[(size_t)(o0 + o) * 512 + kc + sg * 8];
        }
        __syncthreads();
        short8 ah[2], al[2], bh[2], bl[2];
        #pragma unroll
        for (int i = 0; i < 2; ++i) {
            int o = wrow * 32 + i * 16 + lr;
            ah[i] = *(const short8*)&wh_s[o][q * 8];
            al[i] = *(const short8*)&wl_s[o][q * 8];
        }
        #pragma unroll
        for (int j = 0; j < 2; ++j) {
            int m = wcol * 32 + j * 16 + lr;
            #pragma unroll
            for (int t = 0; t < 8; ++t) {
                float f = in_s[q * 8 + t][m];
                unsigned short h = f2bf(f);
                bh[j][t] = (short)h;
                bl[j][t] = (short)f2bf(f - bf2f(h));
            }
        }
        #pragma unroll
        for (int i = 0; i < 2; ++i)
            #pragma unroll
            for (int j = 0; j < 2; ++j) {
                acc[i][j] = mfma_bf16(ah[i], bh[j], acc[i][j]);
                acc[i][j] = mfma_bf16(ah[i], bl[j], acc[i][j]);
                acc[i][j] = mfma_bf16(al[i], bh[j], acc[i][j]);
            }
    }
    #pragma unroll
    for (int i = 0; i < 2; ++i)
        #pragma unroll
        for (int r = 0; r < 4; ++r) {
            int o = o0 + wrow * 32 + i * 16 + q * 4 + r;
            float bo = bias[o];
            #pragma unroll
            for (int j = 0; j < 2; ++j) {
                int m = m0 + wcol * 32 + j * 16 + lr;
                float v = acc[i][j][r] + bo;
                unsigned short vh = f2bf(v);
                float vhf = bf2f(vh);
                float vsq = vhf * vhf;
                unsigned short v2h = f2bf(vsq);
                unsigned short v2l = f2bf(vsq - bf2f(v2h));
                size_t off = (size_t)o * M + m;
                vhT[off] = vh;
                v2hT[off] = v2h;
                v2lT[off] = v2l;
            }
        }
}

// ---------------------------------------------------------------------------
// K2: logits MFMA: S[n][m] = Ah.BhT + Ah.BlT + Al.BhT  (hi/lo bf16 split)
// r1/r6 config — untouched (implicit XCD locality via m-major linear bid).
// ---------------------------------------------------------------------------
__global__ __launch_bounds__(256) void logits_mfma_kernel(
    const unsigned short* __restrict__ Ah, const unsigned short* __restrict__ Al,
    const unsigned short* __restrict__ Bh, const unsigned short* __restrict__ Bl,
    float* __restrict__ S)
{
    __shared__ __align__(16) unsigned short Ah_s[128 * 32];
    __shared__ __align__(16) unsigned short Al_s[128 * 32];
    __shared__ __align__(16) unsigned short Bh_s[128 * 32];
    __shared__ __align__(16) unsigned short Bl_s[128 * 32];
    const int tid = threadIdx.x;
    const int n0 = blockIdx.y * 128, m0 = blockIdx.x * 128;
    const int w = tid >> 6, lane = tid & 63;
    const int wrow = w >> 1, wcol = w & 1;
    const int lr = lane & 15, q = lane >> 4;
    const int srow = lane >> 2, scol = (lane & 3) * 8;   // staging: 16 rows x 64B per instr
    f32x4 acc[4][4];
    #pragma unroll
    for (int i = 0; i < 4; ++i)
        #pragma unroll
        for (int j = 0; j < 4; ++j)
            acc[i][j] = (f32x4){0.f, 0.f, 0.f, 0.f};

    for (int kc = 0; kc < C; kc += 32) {
        __syncthreads();
        #pragma unroll
        for (int g2 = 0; g2 < 2; ++g2) {
            int g = w * 2 + g2;                          // chunk 0..7 (16 rows each)
            size_t ga = (size_t)(n0 + g * 16 + srow) * C + kc + scol;
            size_t gb = (size_t)(m0 + g * 16 + srow) * C + kc + scol;
            int lo = g * 512;                            // 16 rows * 32 shorts
            gload16(&Ah[ga], &Ah_s[lo]);
            gload16(&Al[ga], &Al_s[lo]);
            gload16(&Bh[gb], &Bh_s[lo]);
            gload16(&Bl[gb], &Bl_s[lo]);
        }
        __syncthreads();
        short8 ah[4], al[4], bh[4], bl[4];
        #pragma unroll
        for (int i = 0; i < 4; ++i) {
            int ro = (wrow * 64 + i * 16 + lr) * 32 + q * 8;
            int co = (wcol * 64 + i * 16 + lr) * 32 + q * 8;
            ah[i] = *(const short8*)&Ah_s[ro];
            al[i] = *(const short8*)&Al_s[ro];
            bh[i] = *(const short8*)&Bh_s[co];
            bl[i] = *(const short8*)&Bl_s[co];
        }
        #pragma unroll
        for (int i = 0; i < 4; ++i)
            #pragma unroll
            for (int j = 0; j < 4; ++j) {
                acc[i][j] = mfma_bf16(ah[i], bh[j], acc[i][j]);
                acc[i][j] = mfma_bf16(ah[i], bl[j], acc[i][j]);
                acc[i][j] = mfma_bf16(al[i], bh[j], acc[i][j]);
            }
    }
    #pragma unroll
    for (int i = 0; i < 4; ++i) {
        int nb = n0 + wrow * 64 + i * 16 + q * 4;
        #pragma unroll
        for (int j = 0; j < 4; ++j) {
            int m = m0 + wcol * 64 + j * 16 + lr;
            #pragma unroll
            for (int r = 0; r < 4; ++r)
                S[(size_t)(nb + r) * M + m] = acc[i][j][r];
        }
    }
}

// ---------------------------------------------------------------------------
// K3: row softmax -> bf16 P, rsum = sum of the ROUNDED p (consistency!)
// ---------------------------------------------------------------------------
__global__ __launch_bounds__(256) void rowstat_p_kernel(
    const float* __restrict__ S, unsigned short* __restrict__ P,
    float* __restrict__ rsum)
{
    const int n = blockIdx.x;
    const int tid = threadIdx.x;
    const float* row = S + (size_t)n * M;
    float v[16];
    #pragma unroll
    for (int i = 0; i < 16; ++i) v[i] = row[tid + i * 256];
    float lm = -INFINITY;
    #pragma unroll
    for (int i = 0; i < 16; ++i) lm = fmaxf(lm, v[i]);
    #pragma unroll
    for (int off = 32; off > 0; off >>= 1) lm = fmaxf(lm, __shfl_xor(lm, off, 64));
    __shared__ float red[4];
    __shared__ float redsum[4];
    const int wid = tid >> 6, lane = tid & 63;
    if (lane == 0) red[wid] = lm;
    __syncthreads();
    const float rm = fmaxf(fmaxf(red[0], red[1]), fmaxf(red[2], red[3]));
    float ls = 0.f;
    unsigned short* prow = P + (size_t)n * M;
    #pragma unroll
    for (int i = 0; i < 16; ++i) {
        float p = __expf(v[i] - rm);
        unsigned short pb = f2bf(p);
        prow[tid + i * 256] = pb;
        ls += bf2f(pb);
    }
    #pragma unroll
    for (int off = 32; off > 0; off >>= 1) ls += __shfl_xor(ls, off, 64);
    if (lane == 0) redsum[wid] = ls;
    __syncthreads();
    if (tid == 0) rsum[n] = redsum[0] + redsum[1] + redsum[2] + redsum[3];
}

// ---------------------------------------------------------------------------
// K4: apply partial (split-M). r6 dataflow (5 streams, XCD-grouped) +
// counted-vmcnt double-buffer (T3/T4 minimum):
//   each wave issues exactly 5 gloads/tile; steady state 10 outstanding;
//   vmcnt(5) at iter top drains only tile t's loads -> tile t+1 stays in
//   flight across both raw s_barriers with a full compute phase of cover.
//   Never drains to 0 mid-loop (r3's failure). sched_barrier(0) fences at
//   phase boundaries only; setprio(1) around the MFMA cluster.
// LDS 2x20KB = 40KB -> 4 blocks/CU.
// ---------------------------------------------------------------------------
__global__ __launch_bounds__(256) void apply_partial_kernel(
    const unsigned short* __restrict__ P, const unsigned short* __restrict__ VhT,
    const unsigned short* __restrict__ V2hT, const unsigned short* __restrict__ V2lT,
    float* __restrict__ accm_p, float* __restrict__ acc2_p)
{
    __shared__ __align__(16) unsigned short P_s[2][128 * 32];
    __shared__ __align__(16) unsigned short Vh_s[2][64 * 32];
    __shared__ __align__(16) unsigned short V2h_s[2][64 * 32];
    __shared__ __align__(16) unsigned short V2l_s[2][64 * 32];
    const int tid = threadIdx.x;
    // decode: bid = (group-local j)*8 + xcd; j = glocal*8 + cblk
    const int bid = blockIdx.x;
    const int xcd = bid & 7, j = bid >> 3;            // j: 0..127
    const int c0 = (j & 7) * 64;                      // 8 c-blocks per group
    const int gl = j >> 3;                            // group-local: 0..15
    const int z  = gl >> 2;                           // 4 consecutive groups share z
    const int n0 = (xcd * 4 + (gl & 3)) * 128;        // XCD owns n-rows 4x..4x+3
    const int w = tid >> 6, lane = tid & 63;
    const int wrow = w >> 1, wcol = w & 1;
    const int lr = lane & 15, q = lane >> 4;
    const int srow = lane >> 2, scol = (lane & 3) * 8;
    f32x4 accm[4][2], acc2[4][2];
    #pragma unroll
    for (int i = 0; i < 4; ++i)
        #pragma unroll
        for (int j2 = 0; j2 < 2; ++j2) {
            accm[i][j2] = (f32x4){0.f, 0.f, 0.f, 0.f};
            acc2[i][j2] = (f32x4){0.f, 0.f, 0.f, 0.f};
        }

    const int mbeg = z * (M / MSPLIT);
    const size_t vrow  = (size_t)(c0 + w * 16 + srow) * M + scol;
    const size_t prow0 = (size_t)(n0 + (w * 2)     * 16 + srow) * M + scol;
    const size_t prow1 = (size_t)(n0 + (w * 2 + 1) * 16 + srow) * M + scol;

    auto STAGE = [&](int buf, int mc) {               // exactly 5 loads / wave
        gload16(&P[prow0 + mc],    &P_s[buf][(w * 2)     * 512]);
        gload16(&P[prow1 + mc],    &P_s[buf][(w * 2 + 1) * 512]);
        gload16(&VhT [vrow + mc],  &Vh_s[buf][w * 512]);
        gload16(&V2hT[vrow + mc],  &V2h_s[buf][w * 512]);
        gload16(&V2lT[vrow + mc],  &V2l_s[buf][w * 512]);
    };

    const int NT = (M / MSPLIT) / 32;                 // 32
    STAGE(0, mbeg);
    STAGE(1, mbeg + 32);

    for (int t = 0; t < NT; ++t) {
        if (t < NT - 1) asm volatile("s_waitcnt vmcnt(5)" ::: "memory");
        else            asm volatile("s_waitcnt vmcnt(0)" ::: "memory");
        __builtin_amdgcn_sched_barrier(0);
        __builtin_amdgcn_s_barrier();                 // tile t fully in LDS
        __builtin_amdgcn_sched_barrier(0);
        const int cur = t & 1;
        short8 a[4], bh[2], b2h[2], b2l[2];
        #pragma unroll
        for (int i = 0; i < 4; ++i)
            a[i] = *(const short8*)&P_s[cur][(wrow * 64 + i * 16 + lr) * 32 + q * 8];
        #pragma unroll
        for (int j2 = 0; j2 < 2; ++j2) {
            int off = (wcol * 32 + j2 * 16 + lr) * 32 + q * 8;
            bh[j2]  = *(const short8*)&Vh_s[cur][off];
            b2h[j2] = *(const short8*)&V2h_s[cur][off];
            b2l[j2] = *(const short8*)&V2l_s[cur][off];
        }
        __builtin_amdgcn_s_setprio(1);
        #pragma unroll
        for (int i = 0; i < 4; ++i)
            #pragma unroll
            for (int j2 = 0; j2 < 2; ++j2) {
                accm[i][j2] = mfma_bf16(a[i], bh[j2],  accm[i][j2]);
                acc2[i][j2] = mfma_bf16(a[i], b2h[j2], acc2[i][j2]);
                acc2[i][j2] = mfma_bf16(a[i], b2l[j2], acc2[i][j2]);
            }
        __builtin_amdgcn_s_setprio(0);
        __builtin_amdgcn_sched_barrier(0);
        __builtin_amdgcn_s_barrier();                 // all waves done reading buf[cur]
        __builtin_amdgcn_sched_barrier(0);
        if (t + 2 < NT) STAGE(cur, mbeg + (t + 2) * 32);
    }

    const size_t pbase = (size_t)z * N * C;
    #pragma unroll
    for (int i = 0; i < 4; ++i) {
        int nb = n0 + wrow * 64 + i * 16 + q * 4;
        #pragma unroll
        for (int j2 = 0; j2 < 2; ++j2) {
            int c = c0 + wcol * 32 + j2 * 16 + lr;
            #pragma unroll
            for (int r = 0; r < 4; ++r) {
                size_t off = pbase + (size_t)(nb + r) * C + c;
                accm_p[off] = accm[i][j2][r];
                acc2_p[off] = acc2[i][j2][r];
            }
        }
    }
}

// ---------------------------------------------------------------------------
// K4b: combine partials -> mean/std (fp32). One float4 of c per thread.
// ---------------------------------------------------------------------------
__global__ __launch_bounds__(256) void combine_kernel(
    const float* __restrict__ accm_p, const float* __restrict__ acc2_p,
    const float* __restrict__ rsum, float* __restrict__ meanw,
    float* __restrict__ stdw)
{
    const size_t idx = ((size_t)blockIdx.x * 256 + threadIdx.x) * 4;
    const int n = (int)(idx >> 9);        // /C (C=512)
    const float inv = 1.0f / rsum[n];
    float sm[4] = {0.f, 0.f, 0.f, 0.f}, s2[4] = {0.f, 0.f, 0.f, 0.f};
    #pragma unroll
    for (int z = 0; z < MSPLIT; ++z) {
        float4 a = *(const float4*)&accm_p[(size_t)z * N * C + idx];
        float4 b = *(const float4*)&acc2_p[(size_t)z * N * C + idx];
        sm[0] += a.x; sm[1] += a.y; sm[2] += a.z; sm[3] += a.w;
        s2[0] += b.x; s2[1] += b.y; s2[2] += b.z; s2[3] += b.w;
    }
    float4 mnv, sdv;
    float* mp = (float*)&mnv;
    float* sp = (float*)&sdv;
    #pragma unroll
    for (int k = 0; k < 4; ++k) {
        float mn = sm[k] * inv;
        float m2 = s2[k] * inv;
        mp[k] = mn;
        sp[k] = sqrtf(fmaxf(m2 - mn * mn, 0.f));
    }
    *(float4*)&meanw[idx] = mnv;
    *(float4*)&stdw[idx]  = sdv;
}

// ---------------------------------------------------------------------------
// K5: instance-norm stats per channel (fp32)
// ---------------------------------------------------------------------------
__global__ __launch_bounds__(256) void mvn_kernel(
    const float* __restrict__ content, float* __restrict__ mu, float* __restrict__ rstd)
{
    const int c = blockIdx.x;
    const int tid = threadIdx.x;
    const float* row = content + (size_t)c * N;
    float s = 0.f, ss = 0.f;
    for (int i = tid; i < N; i += 256) {
        float v = row[i];
        s += v;
        ss = fmaf(v, v, ss);
    }
    #pragma unroll
    for (int off = 32; off > 0; off >>= 1) {
        s  += __shfl_xor(s,  off, 64);
        ss += __shfl_xor(ss, off, 64);
    }
    __shared__ float rs[4], rss[4];
    const int wid = tid >> 6, lane = tid & 63;
    if (lane == 0) { rs[wid] = s; rss[wid] = ss; }
    __syncthreads();
    if (tid == 0) {
        float st = rs[0] + rs[1] + rs[2] + rs[3];
        float sst = rss[0] + rss[1] + rss[2] + rss[3];
        float m = st / (float)N;
        float var = (sst - st * st / (float)N) / (float)(N - 1);
        mu[c] = m;
        rstd[c] = rsqrtf(var + 1e-5f);
    }
}

// ---------------------------------------------------------------------------
// K6: final combine (fp32)
// ---------------------------------------------------------------------------
__global__ __launch_bounds__(256) void final_kernel(
    const float* __restrict__ content, const float* __restrict__ meanw,
    const float* __restrict__ stdw, const float* __restrict__ mu,
    const float* __restrict__ rstd, float* __restrict__ out)
{
    __shared__ float mn_s[32][33], sd_s[32][33];
    const int tid = threadIdx.x;
    const int n0 = blockIdx.x * 32;
    const int c0 = blockIdx.y * 32;
    const int tx = tid & 31, ty = tid >> 5;
    #pragma unroll
    for (int i = 0; i < 4; ++i) {
        int n = ty + i * 8;
        mn_s[tx][n] = meanw[(size_t)(n0 + n) * C + c0 + tx];
        sd_s[tx][n] = stdw [(size_t)(n0 + n) * C + c0 + tx];
    }
    __syncthreads();
    #pragma unroll
    for (int i = 0; i < 4; ++i) {
        int c = ty + i * 8;
        float m = mu[c0 + c], r = rstd[c0 + c];
        size_t off = (size_t)(c0 + c) * N + n0 + tx;
        float x = content[off];
        out[off] = sd_s[c][tx] * (x - m) * r + mn_s[c][tx];
    }
}

// ---------------------------------------------------------------------------
extern "C" void kernel_launch(void* const* d_in, const int* in_sizes, int n_in,
                              void* d_out, int out_size, void* d_ws, size_t ws_size,
                              hipStream_t stream)
{
    const float* content = (const float*)d_in[0];
    const float* style   = (const float*)d_in[1];
    const float* ckey    = (const float*)d_in[2];
    const float* skey    = (const float*)d_in[3];
    const float* Wf      = (const float*)d_in[4];
    const float* bf      = (const float*)d_in[5];
    const float* Wg      = (const float*)d_in[6];
    const float* bg      = (const float*)d_in[7];
    const float* Wh      = (const float*)d_in[8];
    const float* bh      = (const float*)d_in[9];
    float* out = (float*)d_out;

    const size_t sz_w  = (size_t)512 * 512 * 2;      // one W half
    const size_t sz_S  = (size_t)N * M * 4;          // 64 MB (aliased by partials)
    const size_t sz_FG = (size_t)N * C * 2;
    const size_t sz_P  = (size_t)N * M * 2;
    const size_t sz_V  = (size_t)C * M * 2;

    char* p = (char*)d_ws;
    auto alloc = [&](size_t bytes) {
        char* r = p;
        p += (bytes + 255) & ~(size_t)255;
        return r;
    };
    unsigned short* WfH = (unsigned short*)alloc(sz_w);
    unsigned short* WfL = (unsigned short*)alloc(sz_w);
    unsigned short* WgH = (unsigned short*)alloc(sz_w);
    unsigned short* WgL = (unsigned short*)alloc(sz_w);
    unsigned short* WhH = (unsigned short*)alloc(sz_w);
    unsigned short* WhL = (unsigned short*)alloc(sz_w);
    float* S = (float*)alloc(sz_S);                  // also: partial accm/acc2
    unsigned short* Fh = (unsigned short*)alloc(sz_FG);
    unsigned short* Fl = (unsigned short*)alloc(sz_FG);
    unsigned short* Gh = (unsigned short*)alloc(sz_FG);
    unsigned short* Gl = (unsigned short*)alloc(sz_FG);
    unsigned short* P    = (unsigned short*)alloc(sz_P);
    unsigned short* VhT  = (unsigned short*)alloc(sz_V);
    unsigned short* V2hT = (unsigned short*)alloc(sz_V);
    unsigned short* V2lT = (unsigned short*)alloc(sz_V);
    float* rsum  = (float*)alloc((size_t)N * 4);
    float* meanw = (float*)alloc((size_t)N * C * 4);
    float* stdw  = (float*)alloc((size_t)N * C * 4);
    float* mu    = (float*)alloc((size_t)C * 4);
    float* rstd  = (float*)alloc((size_t)C * 4);

    // partials alias S (dead between rowstat and next batch's logits):
    // accm_p = MSPLIT*N*C floats, acc2_p = MSPLIT*N*C floats = exactly N*M
    float* accm_p = S;
    float* acc2_p = S + (size_t)MSPLIT * N * C;

    wsplit_kernel<<<dim3(1024), 256, 0, stream>>>(Wf, WfH, WfL);
    wsplit_kernel<<<dim3(1024), 256, 0, stream>>>(Wg, WgH, WgL);
    wsplit_kernel<<<dim3(1024), 256, 0, stream>>>(Wh, WhH, WhL);

    for (int b = 0; b < BATCH; ++b) {
        const size_t fo = (size_t)b * C * N;
        linear_fg_mfma<<<dim3(N / 64, C / 64), 256, 0, stream>>>(ckey + fo, WfH, WfL, bf, Fh, Fl);
        linear_fg_mfma<<<dim3(M / 64, C / 64), 256, 0, stream>>>(skey + fo, WgH, WgL, bg, Gh, Gl);
        linear_v_mfma<<<dim3(M / 64, C / 64), 256, 0, stream>>>(style + fo, WhH, WhL, bh,
                                                                VhT, V2hT, V2lT);
        logits_mfma_kernel<<<dim3(M / 128, N / 128), 256, 0, stream>>>(Fh, Fl, Gh, Gl, S);
        rowstat_p_kernel<<<dim3(N), 256, 0, stream>>>(S, P, rsum);
        apply_partial_kernel<<<dim3(1024), 256, 0, stream>>>(
            P, VhT, V2hT, V2lT, accm_p, acc2_p);
        combine_kernel<<<dim3(N * C / 1024), 256, 0, stream>>>(
            accm_p, acc2_p, rsum, meanw, stdw);
        mvn_kernel<<<dim3(C), 256, 0, stream>>>(content + fo, mu, rstd);
        final_kernel<<<dim3(N / 32, C / 32), 256, 0, stream>>>(
            content + fo, meanw, stdw, mu, rstd, out + fo);
    }
}

// Round 9
// 1017.741 us; speedup vs baseline: 1.0814x; 1.0814x over previous
//
#include <hip/hip_runtime.h>
#include <math.h>

#define BATCH 4
#define C 512
#define N 4096   // content spatial (64*64)
#define M 4096   // style spatial (64*64)
#define MSPLIT 4

typedef __attribute__((ext_vector_type(8))) short short8;
typedef __attribute__((ext_vector_type(8))) __bf16 bf16x8;
typedef __attribute__((ext_vector_type(4))) float f32x4;

static __device__ __forceinline__ unsigned short f2bf(float x) {
    unsigned u = __float_as_uint(x);
    u += 0x7fff + ((u >> 16) & 1);          // round-to-nearest-even
    return (unsigned short)(u >> 16);
}
static __device__ __forceinline__ float bf2f(unsigned short h) {
    return __uint_as_float(((unsigned)h) << 16);
}
static __device__ __forceinline__ f32x4 mfma_bf16(short8 a, short8 b, f32x4 c) {
    return __builtin_amdgcn_mfma_f32_16x16x32_bf16(
        __builtin_bit_cast(bf16x8, a), __builtin_bit_cast(bf16x8, b), c, 0, 0, 0);
}
// direct global->LDS DMA, 16B per lane; lds dest must be wave-uniform base
static __device__ __forceinline__ void gload16(const void* g, void* l) {
    __builtin_amdgcn_global_load_lds(
        (const __attribute__((address_space(1))) void*)g,
        (__attribute__((address_space(3))) void*)l, 16, 0, 0);
}

// ---------------------------------------------------------------------------
// K0: split W (512x512 fp32) into bf16 hi/lo, once per call
// ---------------------------------------------------------------------------
__global__ __launch_bounds__(256) void wsplit_kernel(
    const float* __restrict__ W, unsigned short* __restrict__ hi,
    unsigned short* __restrict__ lo)
{
    int i = blockIdx.x * 256 + threadIdx.x;
    float v = W[i];
    unsigned short h = f2bf(v);
    hi[i] = h;
    lo[i] = f2bf(v - bf2f(h));
}

// ---------------------------------------------------------------------------
// K0b: split THREE fp32 [C][N] slices into bf16 hi/lo TRANSPOSED [N][C].
// Removes all fp32->bf16 repack VALU + scalar LDS reads from the linears.
// Bit-identical split (same f2bf path as the old in-loop conversion).
// ---------------------------------------------------------------------------
__global__ __launch_bounds__(256) void xsplit3_t_kernel(
    const float* __restrict__ in0, const float* __restrict__ in1,
    const float* __restrict__ in2,
    unsigned short* __restrict__ h0, unsigned short* __restrict__ l0,
    unsigned short* __restrict__ h1, unsigned short* __restrict__ l1,
    unsigned short* __restrict__ h2, unsigned short* __restrict__ l2)
{
    __shared__ float ls[64][65];
    const int tid = threadIdx.x;
    const int n0 = blockIdx.x * 64, c0 = blockIdx.y * 64;
    const float* ins[3] = {in0, in1, in2};
    unsigned short* hs[3] = {h0, h1, h2};
    unsigned short* los[3] = {l0, l1, l2};
    #pragma unroll
    for (int t = 0; t < 3; ++t) {
        const float* in = ins[t];
        __syncthreads();                      // protect ls reuse across tensors
        #pragma unroll
        for (int p = 0; p < 4; ++p) {
            int c = p * 16 + (tid >> 4);
            int n = (tid & 15) * 4;
            *(float4*)&ls[c][n] = *(const float4*)&in[(size_t)(c0 + c) * N + n0 + n];
        }
        __syncthreads();
        unsigned short* hp = hs[t];
        unsigned short* lp = los[t];
        #pragma unroll
        for (int p = 0; p < 2; ++p) {
            int n = p * 32 + (tid >> 3);
            int c = (tid & 7) * 8;
            short8 vh, vl;
            #pragma unroll
            for (int e = 0; e < 8; ++e) {
                float f = ls[c + e][n];
                unsigned short h = f2bf(f);
                vh[e] = (short)h;
                vl[e] = (short)f2bf(f - bf2f(h));
            }
            size_t off = (size_t)(n0 + n) * C + c0 + c;
            *(short8*)&hp[off] = vh;
            *(short8*)&lp[off] = vl;
        }
    }
}

// ---------------------------------------------------------------------------
// K1a: linear for Fq/Gt as pure bf16 GEMM on pre-split inputs.
// A = X_t hi/lo [N][C] (n rows), B = W hi/lo [o][k]. 64n x 64o tile, BK=32,
// 4 waves 2x2 (wave tile 32x32), gload_lds staging, unpadded [row][32] LDS.
// out[n][o] hi/lo, o fastest. Bit-identical to the old fused-repack kernel.
// ---------------------------------------------------------------------------
__global__ __launch_bounds__(256) void linear_fg2_mfma(
    const unsigned short* __restrict__ Xh, const unsigned short* __restrict__ Xl,
    const unsigned short* __restrict__ Whi, const unsigned short* __restrict__ Wlo,
    const float* __restrict__ bias,
    unsigned short* __restrict__ out_hi, unsigned short* __restrict__ out_lo)
{
    __shared__ __align__(16) unsigned short Ah_s[64 * 32];
    __shared__ __align__(16) unsigned short Al_s[64 * 32];
    __shared__ __align__(16) unsigned short Bh_s[64 * 32];
    __shared__ __align__(16) unsigned short Bl_s[64 * 32];
    const int tid = threadIdx.x;
    const int n0 = blockIdx.x * 64, o0 = blockIdx.y * 64;
    const int w = tid >> 6, lane = tid & 63;
    const int wrow = w >> 1, wcol = w & 1;
    const int lr = lane & 15, q = lane >> 4;
    const int srow = lane >> 2, scol = (lane & 3) * 8;
    f32x4 acc[2][2];
    #pragma unroll
    for (int i = 0; i < 2; ++i)
        #pragma unroll
        for (int j = 0; j < 2; ++j) acc[i][j] = (f32x4){0.f, 0.f, 0.f, 0.f};

    for (int kc = 0; kc < C; kc += 32) {
        __syncthreads();
        {
            size_t ga = (size_t)(n0 + w * 16 + srow) * C + kc + scol;
            size_t gb = (size_t)(o0 + w * 16 + srow) * 512 + kc + scol;
            gload16(&Xh[ga],  &Ah_s[w * 512]);
            gload16(&Xl[ga],  &Al_s[w * 512]);
            gload16(&Whi[gb], &Bh_s[w * 512]);
            gload16(&Wlo[gb], &Bl_s[w * 512]);
        }
        __syncthreads();
        short8 ah[2], al[2], bh[2], bl[2];
        #pragma unroll
        for (int i = 0; i < 2; ++i) {
            int ro = (wrow * 32 + i * 16 + lr) * 32 + q * 8;
            ah[i] = *(const short8*)&Ah_s[ro];
            al[i] = *(const short8*)&Al_s[ro];
        }
        #pragma unroll
        for (int j = 0; j < 2; ++j) {
            int co = (wcol * 32 + j * 16 + lr) * 32 + q * 8;
            bh[j] = *(const short8*)&Bh_s[co];
            bl[j] = *(const short8*)&Bl_s[co];
        }
        #pragma unroll
        for (int i = 0; i < 2; ++i)
            #pragma unroll
            for (int j = 0; j < 2; ++j) {
                acc[i][j] = mfma_bf16(ah[i], bh[j], acc[i][j]);
                acc[i][j] = mfma_bf16(ah[i], bl[j], acc[i][j]);
                acc[i][j] = mfma_bf16(al[i], bh[j], acc[i][j]);
            }
    }
    #pragma unroll
    for (int i = 0; i < 2; ++i)
        #pragma unroll
        for (int j = 0; j < 2; ++j) {
            int o = o0 + wcol * 32 + j * 16 + lr;
            float bo = bias[o];
            #pragma unroll
            for (int r = 0; r < 4; ++r) {
                int n = n0 + wrow * 32 + i * 16 + q * 4 + r;
                float v = acc[i][j][r] + bo;
                unsigned short h = f2bf(v);
                out_hi[(size_t)n * 512 + o] = h;
                out_lo[(size_t)n * 512 + o] = f2bf(v - bf2f(h));
            }
        }
}

// ---------------------------------------------------------------------------
// K1b: linear for V as pure bf16 GEMM. A = W hi/lo (o rows), B = style_t
// hi/lo [M][C] (m rows). Output transposed [o][m]: vhT + precomputed
// v2hT/v2lT = hi/lo of vh^2 (r6-proven producer-side squaring).
// ---------------------------------------------------------------------------
__global__ __launch_bounds__(256) void linear_v2_mfma(
    const unsigned short* __restrict__ Sh, const unsigned short* __restrict__ Sl,
    const unsigned short* __restrict__ Whi, const unsigned short* __restrict__ Wlo,
    const float* __restrict__ bias,
    unsigned short* __restrict__ vhT, unsigned short* __restrict__ v2hT,
    unsigned short* __restrict__ v2lT)
{
    __shared__ __align__(16) unsigned short Ah_s[64 * 32];
    __shared__ __align__(16) unsigned short Al_s[64 * 32];
    __shared__ __align__(16) unsigned short Bh_s[64 * 32];
    __shared__ __align__(16) unsigned short Bl_s[64 * 32];
    const int tid = threadIdx.x;
    const int m0 = blockIdx.x * 64, o0 = blockIdx.y * 64;
    const int w = tid >> 6, lane = tid & 63;
    const int wrow = w >> 1, wcol = w & 1;
    const int lr = lane & 15, q = lane >> 4;
    const int srow = lane >> 2, scol = (lane & 3) * 8;
    f32x4 acc[2][2];
    #pragma unroll
    for (int i = 0; i < 2; ++i)
        #pragma unroll
        for (int j = 0; j < 2; ++j) acc[i][j] = (f32x4){0.f, 0.f, 0.f, 0.f};

    for (int kc = 0; kc < C; kc += 32) {
        __syncthreads();
        {
            size_t ga = (size_t)(o0 + w * 16 + srow) * 512 + kc + scol;  // W rows
            size_t gb = (size_t)(m0 + w * 16 + srow) * C + kc + scol;    // style_t rows
            gload16(&Whi[ga], &Ah_s[w * 512]);
            gload16(&Wlo[ga], &Al_s[w * 512]);
            gload16(&Sh[gb],  &Bh_s[w * 512]);
            gload16(&Sl[gb],  &Bl_s[w * 512]);
        }
        __syncthreads();
        short8 ah[2], al[2], bh[2], bl[2];
        #pragma unroll
        for (int i = 0; i < 2; ++i) {
            int ro = (wrow * 32 + i * 16 + lr) * 32 + q * 8;
            ah[i] = *(const short8*)&Ah_s[ro];
            al[i] = *(const short8*)&Al_s[ro];
        }
        #pragma unroll
        for (int j = 0; j < 2; ++j) {
            int co = (wcol * 32 + j * 16 + lr) * 32 + q * 8;
            bh[j] = *(const short8*)&Bh_s[co];
            bl[j] = *(const short8*)&Bl_s[co];
        }
        #pragma unroll
        for (int i = 0; i < 2; ++i)
            #pragma unroll
            for (int j = 0; j < 2; ++j) {
                acc[i][j] = mfma_bf16(ah[i], bh[j], acc[i][j]);
                acc[i][j] = mfma_bf16(ah[i], bl[j], acc[i][j]);
                acc[i][j] = mfma_bf16(al[i], bh[j], acc[i][j]);
            }
    }
    #pragma unroll
    for (int i = 0; i < 2; ++i)
        #pragma unroll
        for (int r = 0; r < 4; ++r) {
            int o = o0 + wrow * 32 + i * 16 + q * 4 + r;
            float bo = bias[o];
            #pragma unroll
            for (int j = 0; j < 2; ++j) {
                int m = m0 + wcol * 32 + j * 16 + lr;
                float v = acc[i][j][r] + bo;
                unsigned short vh = f2bf(v);
                float vhf = bf2f(vh);
                float vsq = vhf * vhf;
                unsigned short v2h = f2bf(vsq);
                unsigned short v2l = f2bf(vsq - bf2f(v2h));
                size_t off = (size_t)o * M + m;
                vhT[off] = vh;
                v2hT[off] = v2h;
                v2lT[off] = v2l;
            }
        }
}

// ---------------------------------------------------------------------------
// K2: logits MFMA: S[n][m] = Ah.BhT + Ah.BlT + Al.BhT  (hi/lo bf16 split)
// r1/r6 config — untouched (implicit XCD locality via m-major linear bid).
// ---------------------------------------------------------------------------
__global__ __launch_bounds__(256) void logits_mfma_kernel(
    const unsigned short* __restrict__ Ah, const unsigned short* __restrict__ Al,
    const unsigned short* __restrict__ Bh, const unsigned short* __restrict__ Bl,
    float* __restrict__ S)
{
    __shared__ __align__(16) unsigned short Ah_s[128 * 32];
    __shared__ __align__(16) unsigned short Al_s[128 * 32];
    __shared__ __align__(16) unsigned short Bh_s[128 * 32];
    __shared__ __align__(16) unsigned short Bl_s[128 * 32];
    const int tid = threadIdx.x;
    const int n0 = blockIdx.y * 128, m0 = blockIdx.x * 128;
    const int w = tid >> 6, lane = tid & 63;
    const int wrow = w >> 1, wcol = w & 1;
    const int lr = lane & 15, q = lane >> 4;
    const int srow = lane >> 2, scol = (lane & 3) * 8;   // staging: 16 rows x 64B per instr
    f32x4 acc[4][4];
    #pragma unroll
    for (int i = 0; i < 4; ++i)
        #pragma unroll
        for (int j = 0; j < 4; ++j)
            acc[i][j] = (f32x4){0.f, 0.f, 0.f, 0.f};

    for (int kc = 0; kc < C; kc += 32) {
        __syncthreads();
        #pragma unroll
        for (int g2 = 0; g2 < 2; ++g2) {
            int g = w * 2 + g2;                          // chunk 0..7 (16 rows each)
            size_t ga = (size_t)(n0 + g * 16 + srow) * C + kc + scol;
            size_t gb = (size_t)(m0 + g * 16 + srow) * C + kc + scol;
            int lo = g * 512;                            // 16 rows * 32 shorts
            gload16(&Ah[ga], &Ah_s[lo]);
            gload16(&Al[ga], &Al_s[lo]);
            gload16(&Bh[gb], &Bh_s[lo]);
            gload16(&Bl[gb], &Bl_s[lo]);
        }
        __syncthreads();
        short8 ah[4], al[4], bh[4], bl[4];
        #pragma unroll
        for (int i = 0; i < 4; ++i) {
            int ro = (wrow * 64 + i * 16 + lr) * 32 + q * 8;
            int co = (wcol * 64 + i * 16 + lr) * 32 + q * 8;
            ah[i] = *(const short8*)&Ah_s[ro];
            al[i] = *(const short8*)&Al_s[ro];
            bh[i] = *(const short8*)&Bh_s[co];
            bl[i] = *(const short8*)&Bl_s[co];
        }
        #pragma unroll
        for (int i = 0; i < 4; ++i)
            #pragma unroll
            for (int j = 0; j < 4; ++j) {
                acc[i][j] = mfma_bf16(ah[i], bh[j], acc[i][j]);
                acc[i][j] = mfma_bf16(ah[i], bl[j], acc[i][j]);
                acc[i][j] = mfma_bf16(al[i], bh[j], acc[i][j]);
            }
    }
    #pragma unroll
    for (int i = 0; i < 4; ++i) {
        int nb = n0 + wrow * 64 + i * 16 + q * 4;
        #pragma unroll
        for (int j = 0; j < 4; ++j) {
            int m = m0 + wcol * 64 + j * 16 + lr;
            #pragma unroll
            for (int r = 0; r < 4; ++r)
                S[(size_t)(nb + r) * M + m] = acc[i][j][r];
        }
    }
}

// ---------------------------------------------------------------------------
// K3: row softmax -> bf16 P, rsum = sum of the ROUNDED p (consistency!)
// ---------------------------------------------------------------------------
__global__ __launch_bounds__(256) void rowstat_p_kernel(
    const float* __restrict__ S, unsigned short* __restrict__ P,
    float* __restrict__ rsum)
{
    const int n = blockIdx.x;
    const int tid = threadIdx.x;
    const float* row = S + (size_t)n * M;
    float v[16];
    #pragma unroll
    for (int i = 0; i < 16; ++i) v[i] = row[tid + i * 256];
    float lm = -INFINITY;
    #pragma unroll
    for (int i = 0; i < 16; ++i) lm = fmaxf(lm, v[i]);
    #pragma unroll
    for (int off = 32; off > 0; off >>= 1) lm = fmaxf(lm, __shfl_xor(lm, off, 64));
    __shared__ float red[4];
    __shared__ float redsum[4];
    const int wid = tid >> 6, lane = tid & 63;
    if (lane == 0) red[wid] = lm;
    __syncthreads();
    const float rm = fmaxf(fmaxf(red[0], red[1]), fmaxf(red[2], red[3]));
    float ls = 0.f;
    unsigned short* prow = P + (size_t)n * M;
    #pragma unroll
    for (int i = 0; i < 16; ++i) {
        float p = __expf(v[i] - rm);
        unsigned short pb = f2bf(p);
        prow[tid + i * 256] = pb;
        ls += bf2f(pb);
    }
    #pragma unroll
    for (int off = 32; off > 0; off >>= 1) ls += __shfl_xor(ls, off, 64);
    if (lane == 0) redsum[wid] = ls;
    __syncthreads();
    if (tid == 0) rsum[n] = redsum[0] + redsum[1] + redsum[2] + redsum[3];
}

// ---------------------------------------------------------------------------
// K4: apply partial (split-M). r7 config: 5 streams, XCD-grouped flat grid,
// counted-vmcnt double-buffer (vmcnt(5), never 0 mid-loop), raw s_barriers,
// setprio around MFMA cluster.
// ---------------------------------------------------------------------------
__global__ __launch_bounds__(256) void apply_partial_kernel(
    const unsigned short* __restrict__ P, const unsigned short* __restrict__ VhT,
    const unsigned short* __restrict__ V2hT, const unsigned short* __restrict__ V2lT,
    float* __restrict__ accm_p, float* __restrict__ acc2_p)
{
    __shared__ __align__(16) unsigned short P_s[2][128 * 32];
    __shared__ __align__(16) unsigned short Vh_s[2][64 * 32];
    __shared__ __align__(16) unsigned short V2h_s[2][64 * 32];
    __shared__ __align__(16) unsigned short V2l_s[2][64 * 32];
    const int tid = threadIdx.x;
    const int bid = blockIdx.x;
    const int xcd = bid & 7, j = bid >> 3;            // j: 0..127
    const int c0 = (j & 7) * 64;                      // 8 c-blocks per group
    const int gl = j >> 3;                            // group-local: 0..15
    const int z  = gl >> 2;                           // 4 consecutive groups share z
    const int n0 = (xcd * 4 + (gl & 3)) * 128;        // XCD owns n-rows 4x..4x+3
    const int w = tid >> 6, lane = tid & 63;
    const int wrow = w >> 1, wcol = w & 1;
    const int lr = lane & 15, q = lane >> 4;
    const int srow = lane >> 2, scol = (lane & 3) * 8;
    f32x4 accm[4][2], acc2[4][2];
    #pragma unroll
    for (int i = 0; i < 4; ++i)
        #pragma unroll
        for (int j2 = 0; j2 < 2; ++j2) {
            accm[i][j2] = (f32x4){0.f, 0.f, 0.f, 0.f};
            acc2[i][j2] = (f32x4){0.f, 0.f, 0.f, 0.f};
        }

    const int mbeg = z * (M / MSPLIT);
    const size_t vrow  = (size_t)(c0 + w * 16 + srow) * M + scol;
    const size_t prow0 = (size_t)(n0 + (w * 2)     * 16 + srow) * M + scol;
    const size_t prow1 = (size_t)(n0 + (w * 2 + 1) * 16 + srow) * M + scol;

    auto STAGE = [&](int buf, int mc) {               // exactly 5 loads / wave
        gload16(&P[prow0 + mc],    &P_s[buf][(w * 2)     * 512]);
        gload16(&P[prow1 + mc],    &P_s[buf][(w * 2 + 1) * 512]);
        gload16(&VhT [vrow + mc],  &Vh_s[buf][w * 512]);
        gload16(&V2hT[vrow + mc],  &V2h_s[buf][w * 512]);
        gload16(&V2lT[vrow + mc],  &V2l_s[buf][w * 512]);
    };

    const int NT = (M / MSPLIT) / 32;                 // 32
    STAGE(0, mbeg);
    STAGE(1, mbeg + 32);

    for (int t = 0; t < NT; ++t) {
        if (t < NT - 1) asm volatile("s_waitcnt vmcnt(5)" ::: "memory");
        else            asm volatile("s_waitcnt vmcnt(0)" ::: "memory");
        __builtin_amdgcn_sched_barrier(0);
        __builtin_amdgcn_s_barrier();                 // tile t fully in LDS
        __builtin_amdgcn_sched_barrier(0);
        const int cur = t & 1;
        short8 a[4], bh[2], b2h[2], b2l[2];
        #pragma unroll
        for (int i = 0; i < 4; ++i)
            a[i] = *(const short8*)&P_s[cur][(wrow * 64 + i * 16 + lr) * 32 + q * 8];
        #pragma unroll
        for (int j2 = 0; j2 < 2; ++j2) {
            int off = (wcol * 32 + j2 * 16 + lr) * 32 + q * 8;
            bh[j2]  = *(const short8*)&Vh_s[cur][off];
            b2h[j2] = *(const short8*)&V2h_s[cur][off];
            b2l[j2] = *(const short8*)&V2l_s[cur][off];
        }
        __builtin_amdgcn_s_setprio(1);
        #pragma unroll
        for (int i = 0; i < 4; ++i)
            #pragma unroll
            for (int j2 = 0; j2 < 2; ++j2) {
                accm[i][j2] = mfma_bf16(a[i], bh[j2],  accm[i][j2]);
                acc2[i][j2] = mfma_bf16(a[i], b2h[j2], acc2[i][j2]);
                acc2[i][j2] = mfma_bf16(a[i], b2l[j2], acc2[i][j2]);
            }
        __builtin_amdgcn_s_setprio(0);
        __builtin_amdgcn_sched_barrier(0);
        __builtin_amdgcn_s_barrier();                 // all waves done reading buf[cur]
        __builtin_amdgcn_sched_barrier(0);
        if (t + 2 < NT) STAGE(cur, mbeg + (t + 2) * 32);
    }

    const size_t pbase = (size_t)z * N * C;
    #pragma unroll
    for (int i = 0; i < 4; ++i) {
        int nb = n0 + wrow * 64 + i * 16 + q * 4;
        #pragma unroll
        for (int j2 = 0; j2 < 2; ++j2) {
            int c = c0 + wcol * 32 + j2 * 16 + lr;
            #pragma unroll
            for (int r = 0; r < 4; ++r) {
                size_t off = pbase + (size_t)(nb + r) * C + c;
                accm_p[off] = accm[i][j2][r];
                acc2_p[off] = acc2[i][j2][r];
            }
        }
    }
}

// ---------------------------------------------------------------------------
// K4b: combine partials -> mean/std (fp32). One float4 of c per thread.
// ---------------------------------------------------------------------------
__global__ __launch_bounds__(256) void combine_kernel(
    const float* __restrict__ accm_p, const float* __restrict__ acc2_p,
    const float* __restrict__ rsum, float* __restrict__ meanw,
    float* __restrict__ stdw)
{
    const size_t idx = ((size_t)blockIdx.x * 256 + threadIdx.x) * 4;
    const int n = (int)(idx >> 9);        // /C (C=512)
    const float inv = 1.0f / rsum[n];
    float sm[4] = {0.f, 0.f, 0.f, 0.f}, s2[4] = {0.f, 0.f, 0.f, 0.f};
    #pragma unroll
    for (int z = 0; z < MSPLIT; ++z) {
        float4 a = *(const float4*)&accm_p[(size_t)z * N * C + idx];
        float4 b = *(const float4*)&acc2_p[(size_t)z * N * C + idx];
        sm[0] += a.x; sm[1] += a.y; sm[2] += a.z; sm[3] += a.w;
        s2[0] += b.x; s2[1] += b.y; s2[2] += b.z; s2[3] += b.w;
    }
    float4 mnv, sdv;
    float* mp = (float*)&mnv;
    float* sp = (float*)&sdv;
    #pragma unroll
    for (int k = 0; k < 4; ++k) {
        float mn = sm[k] * inv;
        float m2 = s2[k] * inv;
        mp[k] = mn;
        sp[k] = sqrtf(fmaxf(m2 - mn * mn, 0.f));
    }
    *(float4*)&meanw[idx] = mnv;
    *(float4*)&stdw[idx]  = sdv;
}

// ---------------------------------------------------------------------------
// K5: instance-norm stats per channel (fp32)
// ---------------------------------------------------------------------------
__global__ __launch_bounds__(256) void mvn_kernel(
    const float* __restrict__ content, float* __restrict__ mu, float* __restrict__ rstd)
{
    const int c = blockIdx.x;
    const int tid = threadIdx.x;
    const float* row = content + (size_t)c * N;
    float s = 0.f, ss = 0.f;
    for (int i = tid; i < N; i += 256) {
        float v = row[i];
        s += v;
        ss = fmaf(v, v, ss);
    }
    #pragma unroll
    for (int off = 32; off > 0; off >>= 1) {
        s  += __shfl_xor(s,  off, 64);
        ss += __shfl_xor(ss, off, 64);
    }
    __shared__ float rs[4], rss[4];
    const int wid = tid >> 6, lane = tid & 63;
    if (lane == 0) { rs[wid] = s; rss[wid] = ss; }
    __syncthreads();
    if (tid == 0) {
        float st = rs[0] + rs[1] + rs[2] + rs[3];
        float sst = rss[0] + rss[1] + rss[2] + rss[3];
        float m = st / (float)N;
        float var = (sst - st * st / (float)N) / (float)(N - 1);
        mu[c] = m;
        rstd[c] = rsqrtf(var + 1e-5f);
    }
}

// ---------------------------------------------------------------------------
// K6: final combine (fp32)
// ---------------------------------------------------------------------------
__global__ __launch_bounds__(256) void final_kernel(
    const float* __restrict__ content, const float* __restrict__ meanw,
    const float* __restrict__ stdw, const float* __restrict__ mu,
    const float* __restrict__ rstd, float* __restrict__ out)
{
    __shared__ float mn_s[32][33], sd_s[32][33];
    const int tid = threadIdx.x;
    const int n0 = blockIdx.x * 32;
    const int c0 = blockIdx.y * 32;
    const int tx = tid & 31, ty = tid >> 5;
    #pragma unroll
    for (int i = 0; i < 4; ++i) {
        int n = ty + i * 8;
        mn_s[tx][n] = meanw[(size_t)(n0 + n) * C + c0 + tx];
        sd_s[tx][n] = stdw [(size_t)(n0 + n) * C + c0 + tx];
    }
    __syncthreads();
    #pragma unroll
    for (int i = 0; i < 4; ++i) {
        int c = ty + i * 8;
        float m = mu[c0 + c], r = rstd[c0 + c];
        size_t off = (size_t)(c0 + c) * N + n0 + tx;
        float x = content[off];
        out[off] = sd_s[c][tx] * (x - m) * r + mn_s[c][tx];
    }
}

// ---------------------------------------------------------------------------
extern "C" void kernel_launch(void* const* d_in, const int* in_sizes, int n_in,
                              void* d_out, int out_size, void* d_ws, size_t ws_size,
                              hipStream_t stream)
{
    const float* content = (const float*)d_in[0];
    const float* style   = (const float*)d_in[1];
    const float* ckey    = (const float*)d_in[2];
    const float* skey    = (const float*)d_in[3];
    const float* Wf      = (const float*)d_in[4];
    const float* bf      = (const float*)d_in[5];
    const float* Wg      = (const float*)d_in[6];
    const float* bg      = (const float*)d_in[7];
    const float* Wh      = (const float*)d_in[8];
    const float* bh      = (const float*)d_in[9];
    float* out = (float*)d_out;

    const size_t sz_w  = (size_t)512 * 512 * 2;      // one W half
    const size_t sz_S  = (size_t)N * M * 4;          // 64 MB (aliased by partials + X splits)
    const size_t sz_FG = (size_t)N * C * 2;
    const size_t sz_P  = (size_t)N * M * 2;
    const size_t sz_V  = (size_t)C * M * 2;
    const size_t sz_X  = (size_t)N * C * 2;          // one transposed input half (4 MB)

    char* p = (char*)d_ws;
    auto alloc = [&](size_t bytes) {
        char* r = p;
        p += (bytes + 255) & ~(size_t)255;
        return r;
    };
    unsigned short* WfH = (unsigned short*)alloc(sz_w);
    unsigned short* WfL = (unsigned short*)alloc(sz_w);
    unsigned short* WgH = (unsigned short*)alloc(sz_w);
    unsigned short* WgL = (unsigned short*)alloc(sz_w);
    unsigned short* WhH = (unsigned short*)alloc(sz_w);
    unsigned short* WhL = (unsigned short*)alloc(sz_w);
    float* S = (float*)alloc(sz_S);                  // also: partials + X splits
    unsigned short* Fh = (unsigned short*)alloc(sz_FG);
    unsigned short* Fl = (unsigned short*)alloc(sz_FG);
    unsigned short* Gh = (unsigned short*)alloc(sz_FG);
    unsigned short* Gl = (unsigned short*)alloc(sz_FG);
    unsigned short* P    = (unsigned short*)alloc(sz_P);
    unsigned short* VhT  = (unsigned short*)alloc(sz_V);
    unsigned short* V2hT = (unsigned short*)alloc(sz_V);
    unsigned short* V2lT = (unsigned short*)alloc(sz_V);
    float* rsum  = (float*)alloc((size_t)N * 4);
    float* meanw = (float*)alloc((size_t)N * C * 4);
    float* stdw  = (float*)alloc((size_t)N * C * 4);
    float* mu    = (float*)alloc((size_t)C * 4);
    float* rstd  = (float*)alloc((size_t)C * 4);

    // partials alias S (dead between rowstat and next batch's logits):
    // accm_p = MSPLIT*N*C floats, acc2_p = MSPLIT*N*C floats = exactly N*M
    float* accm_p = S;
    float* acc2_p = S + (size_t)MSPLIT * N * C;

    // transposed input splits alias the TAIL 24MB of the 64MB S region:
    // written at batch start (after prev batch's combine consumed partials),
    // consumed by the linears, then logits overwrites the whole S region.
    // Stream-ordered lifetimes -> safe; keeps workspace at the r7 footprint.
    char* xbase = (char*)S + (sz_S - 6 * sz_X);
    unsigned short* CkH = (unsigned short*)(xbase + 0 * sz_X);
    unsigned short* CkL = (unsigned short*)(xbase + 1 * sz_X);
    unsigned short* SkH = (unsigned short*)(xbase + 2 * sz_X);
    unsigned short* SkL = (unsigned short*)(xbase + 3 * sz_X);
    unsigned short* StH = (unsigned short*)(xbase + 4 * sz_X);
    unsigned short* StL = (unsigned short*)(xbase + 5 * sz_X);

    wsplit_kernel<<<dim3(1024), 256, 0, stream>>>(Wf, WfH, WfL);
    wsplit_kernel<<<dim3(1024), 256, 0, stream>>>(Wg, WgH, WgL);
    wsplit_kernel<<<dim3(1024), 256, 0, stream>>>(Wh, WhH, WhL);

    for (int b = 0; b < BATCH; ++b) {
        const size_t fo = (size_t)b * C * N;
        xsplit3_t_kernel<<<dim3(N / 64, C / 64), 256, 0, stream>>>(
            ckey + fo, skey + fo, style + fo, CkH, CkL, SkH, SkL, StH, StL);
        linear_fg2_mfma<<<dim3(N / 64, C / 64), 256, 0, stream>>>(
            CkH, CkL, WfH, WfL, bf, Fh, Fl);
        linear_fg2_mfma<<<dim3(M / 64, C / 64), 256, 0, stream>>>(
            SkH, SkL, WgH, WgL, bg, Gh, Gl);
        linear_v2_mfma<<<dim3(M / 64, C / 64), 256, 0, stream>>>(
            StH, StL, WhH, WhL, bh, VhT, V2hT, V2lT);
        logits_mfma_kernel<<<dim3(M / 128, N / 128), 256, 0, stream>>>(Fh, Fl, Gh, Gl, S);
        rowstat_p_kernel<<<dim3(N), 256, 0, stream>>>(S, P, rsum);
        apply_partial_kernel<<<dim3(1024), 256, 0, stream>>>(
            P, VhT, V2hT, V2lT, accm_p, acc2_p);
        combine_kernel<<<dim3(N * C / 1024), 256, 0, stream>>>(
            accm_p, acc2_p, rsum, meanw, stdw);
        mvn_kernel<<<dim3(C), 256, 0, stream>>>(content + fo, mu, rstd);
        final_kernel<<<dim3(N / 32, C / 32), 256, 0, stream>>>(
            content + fo, meanw, stdw, mu, rstd, out + fo);
    }
}